// Round 8
// baseline (1334.021 us; speedup 1.0000x reference)
//
#include <hip/hip_runtime.h>
#include <hip/hip_bf16.h>

#define N_NODES 50000
#define N_EDGES 300000
#define DIM 256
#define MPAD 50048   // 391 * 128

typedef __attribute__((ext_vector_type(8))) _Float16 half8;
typedef __attribute__((ext_vector_type(4))) _Float16 half4;
typedef __attribute__((ext_vector_type(4))) float f32x4;

__device__ __forceinline__ void async16(const void* g, void* l) {
    __builtin_amdgcn_global_load_lds(
        (const __attribute__((address_space(1))) unsigned int*)g,
        (__attribute__((address_space(3))) unsigned int*)l, 16, 0, 0);
}

// ---------------------------------------------------------------------------
// Per-thread BN finalize from 8 replicated stat buffers (d = tid, 256 wide).
// Used in-block ONLY by low-block-count consumers (gemm_bn: 782 blocks,
// ~12.5 MB L2). Round-7 measured: fusing this into 12500-block consumers
// (gather_bn/bn_apply_f) costs ~1 GB of redundant reads -> regression.
// ---------------------------------------------------------------------------
__device__ __forceinline__ void bn_finalize_thread(const float* __restrict__ st,
                                                   const float* __restrict__ g,
                                                   const float* __restrict__ beta,
                                                   float* scshL, int d, int n) {
    float s = 0.0f, sq = 0.0f;
#pragma unroll
    for (int r = 0; r < 8; r++) {
        s += st[r * 512 + d];
        sq += st[r * 512 + 256 + d];
    }
    float invn = 1.0f / (float)n;
    float mean = s * invn;
    float var = sq * invn - mean * mean;
    float inv = rsqrtf(var + 1e-5f);
    float scale = g[d] * inv;
    scshL[d] = scale;
    scshL[256 + d] = beta[d] - mean * scale;
}

// ---------------------------------------------------------------------------
// CSR build: histogram
// ---------------------------------------------------------------------------
__global__ __launch_bounds__(256) void hist_dst(const int* __restrict__ dst,
                                                int* __restrict__ deg, int E) {
    int e = blockIdx.x * blockDim.x + threadIdx.x;
    if (e < E) atomicAdd(&deg[dst[e]], 1);
}

// ---------------------------------------------------------------------------
// Hierarchical scan, step 1: per-block (1024) exclusive scan via wave shuffles.
// ---------------------------------------------------------------------------
__global__ __launch_bounds__(1024) void scan_blk(const int* __restrict__ deg,
                                                 int* __restrict__ ptr,
                                                 int* __restrict__ bsum, int n) {
    __shared__ int wsum[16];
    __shared__ int wpre[16];
    int tid = threadIdx.x;
    int i = blockIdx.x * 1024 + tid;
    int v = (i < n) ? deg[i] : 0;
    int lane = tid & 63, w = tid >> 6;
    int s = v;
#pragma unroll
    for (int off = 1; off < 64; off <<= 1) {
        int t = __shfl_up(s, off, 64);
        if (lane >= off) s += t;
    }
    if (lane == 63) wsum[w] = s;
    __syncthreads();
    if (tid < 16) {
        int acc = 0;
        for (int j = 0; j < tid; j++) acc += wsum[j];
        wpre[tid] = acc;
    }
    __syncthreads();
    int incl = s + wpre[w];
    if (i < n) ptr[i] = incl - v;
    if (tid == 1023) bsum[blockIdx.x] = incl;
}

// ---------------------------------------------------------------------------
// Scan step 2: each block redundantly reduces the block totals below it,
// adds offset, duplicates to cursor.
// ---------------------------------------------------------------------------
__global__ __launch_bounds__(1024) void scan_add(int* __restrict__ ptr,
                                                 const int* __restrict__ bsum,
                                                 int* __restrict__ cursor,
                                                 int n, int E) {
    __shared__ int soff;
    int tid = threadIdx.x;
    if (tid < 64) {
        int v = (tid < (int)blockIdx.x) ? bsum[tid] : 0;
#pragma unroll
        for (int off = 32; off > 0; off >>= 1) v += __shfl_down(v, off, 64);
        if (tid == 0) soff = v;
    }
    __syncthreads();
    int i = blockIdx.x * 1024 + tid;
    if (i < n) {
        int val = ptr[i] + soff;
        ptr[i] = val;
        cursor[i] = val;
    }
    if (i == n) ptr[n] = E;
}

// ---------------------------------------------------------------------------
// CSR build: counting-sort scatter
// ---------------------------------------------------------------------------
__global__ __launch_bounds__(256) void scatter_src(const int* __restrict__ src,
                                                   const int* __restrict__ dst,
                                                   int* __restrict__ cursor,
                                                   int* __restrict__ srcbuf, int E) {
    int e = blockIdx.x * blockDim.x + threadIdx.x;
    if (e < E) {
        int pos = atomicAdd(&cursor[dst[e]], 1);
        srcbuf[pos] = src[e];
    }
}

// ---------------------------------------------------------------------------
// Fused prep: blocks [0,160) transpose W (fp32->fp16 [N][K]); the rest
// convert x (fp32) -> fp16.
// ---------------------------------------------------------------------------
__global__ __launch_bounds__(256) void prep(const float* __restrict__ W1,
                                            const float* __restrict__ W2,
                                            _Float16* __restrict__ Wt,
                                            const float* __restrict__ x,
                                            _Float16* __restrict__ hb) {
    __shared__ float tile[64][65];
    int tid = threadIdx.x;
    if (blockIdx.x < 160) {
        int mat = blockIdx.x >> 4;
        int t = blockIdx.x & 15;
        int tr = t >> 2, tc = t & 3;
        const float* W = (mat < 5) ? (W1 + (size_t)mat * 65536)
                                   : (W2 + (size_t)(mat - 5) * 65536);
        int c = tid & 63, r0 = tid >> 6;
#pragma unroll 4
        for (int i = 0; i < 16; i++) {
            int r = r0 + i * 4;
            tile[r][c] = W[(size_t)(tr * 64 + r) * 256 + tc * 64 + c];
        }
        __syncthreads();
        _Float16* o = Wt + (size_t)mat * 65536;
#pragma unroll 4
        for (int i = 0; i < 16; i++) {
            int r = r0 + i * 4;
            o[(size_t)(tc * 64 + r) * 256 + tr * 64 + c] = (_Float16)tile[c][r];
        }
    } else {
        size_t i = (size_t)(blockIdx.x - 160) * 256 + tid;  // float4 index
        float4 v = ((const float4*)x)[i];
        half4 o;
        o.x = (_Float16)v.x; o.y = (_Float16)v.y;
        o.z = (_Float16)v.z; o.w = (_Float16)v.w;
        ((half4*)hb)[i] = o;
    }
}

// ---------------------------------------------------------------------------
// Layer-0 gather (fp16 x): z[n] = (1+eps)*xh[n] + sum relu(xh[src]).
// ---------------------------------------------------------------------------
__global__ __launch_bounds__(256) void gather_h(const _Float16* __restrict__ h,
                                                const int* __restrict__ ptr,
                                                const int* __restrict__ srcbuf,
                                                _Float16* __restrict__ z,
                                                const float* __restrict__ eps) {
    int node = blockIdx.x * 4 + (threadIdx.x >> 6);
    if (node >= N_NODES) return;
    int lane = threadIdx.x & 63;
    int beg = ptr[node], end = ptr[node + 1];
    float s = 1.0f + eps[0];
    half4 hv = ((const half4*)(h + (size_t)node * DIM))[lane];
    float a0 = (float)hv.x * s, a1 = (float)hv.y * s;
    float a2 = (float)hv.z * s, a3 = (float)hv.w * s;
    int e = beg;
    for (; e + 4 <= end; e += 4) {
        int s0 = srcbuf[e], s1 = srcbuf[e + 1], s2 = srcbuf[e + 2], s3 = srcbuf[e + 3];
        half4 v0 = ((const half4*)(h + (size_t)s0 * DIM))[lane];
        half4 v1 = ((const half4*)(h + (size_t)s1 * DIM))[lane];
        half4 v2 = ((const half4*)(h + (size_t)s2 * DIM))[lane];
        half4 v3 = ((const half4*)(h + (size_t)s3 * DIM))[lane];
        a0 += fmaxf((float)v0.x, 0.f) + fmaxf((float)v1.x, 0.f)
            + fmaxf((float)v2.x, 0.f) + fmaxf((float)v3.x, 0.f);
        a1 += fmaxf((float)v0.y, 0.f) + fmaxf((float)v1.y, 0.f)
            + fmaxf((float)v2.y, 0.f) + fmaxf((float)v3.y, 0.f);
        a2 += fmaxf((float)v0.z, 0.f) + fmaxf((float)v1.z, 0.f)
            + fmaxf((float)v2.z, 0.f) + fmaxf((float)v3.z, 0.f);
        a3 += fmaxf((float)v0.w, 0.f) + fmaxf((float)v1.w, 0.f)
            + fmaxf((float)v2.w, 0.f) + fmaxf((float)v3.w, 0.f);
    }
    for (; e < end; e++) {
        half4 v = ((const half4*)(h + (size_t)srcbuf[e] * DIM))[lane];
        a0 += fmaxf((float)v.x, 0.f); a1 += fmaxf((float)v.y, 0.f);
        a2 += fmaxf((float)v.z, 0.f); a3 += fmaxf((float)v.w, 0.f);
    }
    half4 o;
    o.x = (_Float16)a0; o.y = (_Float16)a1;
    o.z = (_Float16)a2; o.w = (_Float16)a3;
    ((half4*)(z + (size_t)node * DIM))[lane] = o;
}

// ---------------------------------------------------------------------------
// Layers 1..4 gather with fused BN2 (scale/shift precomputed by bn_finalize):
// h = relu(scale*C + shift) on the fly.  [round-6 form, measured best]
// ---------------------------------------------------------------------------
__global__ __launch_bounds__(256) void gather_bn(const _Float16* __restrict__ C,
                                                 const int* __restrict__ ptr,
                                                 const int* __restrict__ srcbuf,
                                                 _Float16* __restrict__ z,
                                                 const float* __restrict__ scsh,
                                                 const float* __restrict__ eps,
                                                 int l) {
    int node = blockIdx.x * 4 + (threadIdx.x >> 6);
    if (node >= N_NODES) return;
    int lane = threadIdx.x & 63;
    float4 sc = ((const float4*)scsh)[lane];
    float4 sh = ((const float4*)(scsh + DIM))[lane];
    int beg = ptr[node], end = ptr[node + 1];
    float s = 1.0f + eps[l];
    half4 hv = ((const half4*)(C + (size_t)node * DIM))[lane];
    float a0 = s * fmaxf((float)hv.x * sc.x + sh.x, 0.f);
    float a1 = s * fmaxf((float)hv.y * sc.y + sh.y, 0.f);
    float a2 = s * fmaxf((float)hv.z * sc.z + sh.z, 0.f);
    float a3 = s * fmaxf((float)hv.w * sc.w + sh.w, 0.f);
    int e = beg;
    for (; e + 4 <= end; e += 4) {
        int s0 = srcbuf[e], s1 = srcbuf[e + 1], s2 = srcbuf[e + 2], s3 = srcbuf[e + 3];
        half4 v0 = ((const half4*)(C + (size_t)s0 * DIM))[lane];
        half4 v1 = ((const half4*)(C + (size_t)s1 * DIM))[lane];
        half4 v2 = ((const half4*)(C + (size_t)s2 * DIM))[lane];
        half4 v3 = ((const half4*)(C + (size_t)s3 * DIM))[lane];
        a0 += fmaxf((float)v0.x * sc.x + sh.x, 0.f) + fmaxf((float)v1.x * sc.x + sh.x, 0.f)
            + fmaxf((float)v2.x * sc.x + sh.x, 0.f) + fmaxf((float)v3.x * sc.x + sh.x, 0.f);
        a1 += fmaxf((float)v0.y * sc.y + sh.y, 0.f) + fmaxf((float)v1.y * sc.y + sh.y, 0.f)
            + fmaxf((float)v2.y * sc.y + sh.y, 0.f) + fmaxf((float)v3.y * sc.y + sh.y, 0.f);
        a2 += fmaxf((float)v0.z * sc.z + sh.z, 0.f) + fmaxf((float)v1.z * sc.z + sh.z, 0.f)
            + fmaxf((float)v2.z * sc.z + sh.z, 0.f) + fmaxf((float)v3.z * sc.z + sh.z, 0.f);
        a3 += fmaxf((float)v0.w * sc.w + sh.w, 0.f) + fmaxf((float)v1.w * sc.w + sh.w, 0.f)
            + fmaxf((float)v2.w * sc.w + sh.w, 0.f) + fmaxf((float)v3.w * sc.w + sh.w, 0.f);
    }
    for (; e < end; e++) {
        half4 v = ((const half4*)(C + (size_t)srcbuf[e] * DIM))[lane];
        a0 += fmaxf((float)v.x * sc.x + sh.x, 0.f);
        a1 += fmaxf((float)v.y * sc.y + sh.y, 0.f);
        a2 += fmaxf((float)v.z * sc.z + sh.z, 0.f);
        a3 += fmaxf((float)v.w * sc.w + sh.w, 0.f);
    }
    half4 o;
    o.x = (_Float16)a0; o.y = (_Float16)a1;
    o.z = (_Float16)a2; o.w = (_Float16)a3;
    ((half4*)(z + (size_t)node * DIM))[lane] = o;
}

// ===========================================================================
// GEMM: 128x128 tile, BK=64 (4 K-steps), XOR-swizzled LDS staging,
// 4 blocks/CU.  NEW: per-block K-step ROTATION (kr = (ko + by) & 3) --
// K-accumulation is commutative, so each block walks the 4 K-quarters in a
// rotated order, staggering the global_load_lds bursts across blocks to
// break the stage->drain convoy (hbm_pct was 13% on a 51MB kernel).
// ===========================================================================
#define GEMM_EPILOGUE                                                        \
    __syncthreads();                                                         \
    float* colsum = (float*)((char*)smem + 34816);                           \
    float* colsq = colsum + 128;                                             \
    if (tid < 128) { colsum[tid] = 0.0f; colsq[tid] = 0.0f; }                \
    _Float16* Cs = (_Float16*)smem;                                          \
    float bcol[4];                                                           \
    _Pragma("unroll")                                                        \
    for (int j = 0; j < 4; j++) bcol[j] = bias[col0 + wn + j * 16 + lrow];   \
    float csum[4] = {0.f, 0.f, 0.f, 0.f};                                    \
    float csq[4] = {0.f, 0.f, 0.f, 0.f};                                     \
    _Pragma("unroll")                                                        \
    for (int i = 0; i < 4; i++) {                                            \
        int rl = wm + i * 16 + quad * 4;                                     \
        _Pragma("unroll")                                                    \
        for (int j = 0; j < 4; j++) {                                        \
            int cl = wn + j * 16 + lrow;                                     \
            _Pragma("unroll")                                                \
            for (int r = 0; r < 4; r++) {                                    \
                float v = acc[i][j][r] + bcol[j];                            \
                Cs[(rl + r) * 136 + cl] = (_Float16)v;                       \
                if (row0 + rl + r < M) { csum[j] += v; csq[j] += v * v; }    \
            }                                                                \
        }                                                                    \
    }                                                                        \
    __syncthreads();                                                         \
    {                                                                        \
        int rgrp = lane >> 4, ch = lane & 15;                                \
        _Pragma("unroll")                                                    \
        for (int it = 0; it < 8; it++) {                                     \
            int row = wid * 32 + it * 4 + rgrp;                              \
            uint4 vv = *(const uint4*)(Cs + row * 136 + ch * 8);             \
            *(uint4*)(C + (size_t)(row0 + row) * DIM + col0 + ch * 8) = vv;  \
        }                                                                    \
    }                                                                        \
    _Pragma("unroll")                                                        \
    for (int j = 0; j < 4; j++) {                                            \
        atomicAdd(&colsum[wn + j * 16 + lrow], csum[j]);                     \
        atomicAdd(&colsq[wn + j * 16 + lrow], csq[j]);                       \
    }                                                                        \
    __syncthreads();                                                         \
    if (tid < 128) {                                                         \
        float* st = stats + (blockIdx.y & 7) * 512;                          \
        atomicAdd(&st[col0 + tid], colsum[tid]);                             \
        atomicAdd(&st[DIM + col0 + tid], colsq[tid]);                        \
    }

__global__ __launch_bounds__(256) void gemm_f16(const _Float16* __restrict__ A,
                                                const _Float16* __restrict__ Wt,
                                                const float* __restrict__ bias,
                                                _Float16* __restrict__ C,
                                                float* __restrict__ stats,
                                                int M) {
    __shared__ uint4 smem[2240];  // 35840 B: A 16K | B 16K (epi: 34816+1024)

    int tid = threadIdx.x;
    int wid = tid >> 6, lane = tid & 63;
    int quad = lane >> 4, lrow = lane & 15;
    int row0 = blockIdx.y * 128, col0 = blockIdx.x * 128;
    int wm = (wid & 1) * 64, wn = (wid >> 1) * 64;
    int krot = blockIdx.y & 3;

    f32x4 acc[4][4] = {};
    const char* Ab = (const char*)A;
    const char* Bb = (const char*)Wt;

#pragma unroll
    for (int ko = 0; ko < 4; ko++) {
        int kr = (ko + krot) & 3;
        int kb0 = kr * 128;  // byte offset of this K-quarter within a 512B row
#pragma unroll
        for (int j = 0; j < 4; j++) {
            int sbase = wid * 256 + j * 64;   // 16B-slot base (wave-uniform)
            int s = sbase + lane;
            int m = s >> 3;                   // row 0..127
            int c = (s & 7) ^ (m & 7);        // swizzled slot 0..7
            size_t go = (size_t)(row0 + m) * 512 + kb0 + c * 16;
            async16(Ab + go, (char*)smem + sbase * 16);
            size_t gob = (size_t)(col0 + m) * 512 + kb0 + c * 16;
            async16(Bb + gob, (char*)smem + 16384 + sbase * 16);
        }
        __syncthreads();
#pragma unroll
        for (int kc = 0; kc < 2; kc++) {
            half8 af[4], bf[4];
#pragma unroll
            for (int t = 0; t < 4; t++) {
                int ma = wm + t * 16 + lrow;
                int ca = kc * 4 + quad;       // 0..7
                af[t] = *(const half8*)((const char*)smem +
                                        (ma * 8 + (ca ^ (ma & 7))) * 16);
                int mb = wn + t * 16 + lrow;
                bf[t] = *(const half8*)((const char*)smem + 16384 +
                                        (mb * 8 + (ca ^ (mb & 7))) * 16);
            }
#pragma unroll
            for (int i = 0; i < 4; i++)
#pragma unroll
                for (int j2 = 0; j2 < 4; j2++)
                    acc[i][j2] = __builtin_amdgcn_mfma_f32_16x16x32_f16(
                        af[i], bf[j2], acc[i][j2], 0, 0, 0);
        }
        if (ko < 3) __syncthreads();
    }

    GEMM_EPILOGUE
}

// Same GEMM with K-rotation; BN1 finalized IN-BLOCK from statsIn (782 blocks
// x 16KB = cheap) into LDS, applied to the A-operand as scale/shift+ReLU.
__global__ __launch_bounds__(256) void gemm_bn(const _Float16* __restrict__ A,
                                               const _Float16* __restrict__ Wt,
                                               const float* __restrict__ bias,
                                               _Float16* __restrict__ C,
                                               float* __restrict__ stats,
                                               const float* __restrict__ statsIn,
                                               const float* __restrict__ gamma1,
                                               const float* __restrict__ beta1,
                                               int M) {
    __shared__ uint4 smem[2368];  // 35840 B staging/epi + 2048 B scshL

    int tid = threadIdx.x;
    int wid = tid >> 6, lane = tid & 63;
    int quad = lane >> 4, lrow = lane & 15;
    int row0 = blockIdx.y * 128, col0 = blockIdx.x * 128;
    int wm = (wid & 1) * 64, wn = (wid >> 1) * 64;
    int krot = blockIdx.y & 3;

    // In-block BN1 finalize -> LDS (region disjoint from staging/epilogue)
    float* scshL = (float*)((char*)smem + 35840);
    bn_finalize_thread(statsIn, gamma1, beta1, scshL, tid, M);
    __syncthreads();

    // Per-lane BN1 scale/shift fragments for all 8 k-chunks (fp16, regs)
    half8 scv[8], shv[8];
#pragma unroll
    for (int cc = 0; cc < 8; cc++) {
        int kk = cc * 32 + quad * 8;
        float4 s0 = *(const float4*)(scshL + kk);
        float4 s1 = *(const float4*)(scshL + kk + 4);
        float4 h0 = *(const float4*)(scshL + DIM + kk);
        float4 h1 = *(const float4*)(scshL + DIM + kk + 4);
        half8 sv = {(_Float16)s0.x, (_Float16)s0.y, (_Float16)s0.z, (_Float16)s0.w,
                    (_Float16)s1.x, (_Float16)s1.y, (_Float16)s1.z, (_Float16)s1.w};
        half8 hv = {(_Float16)h0.x, (_Float16)h0.y, (_Float16)h0.z, (_Float16)h0.w,
                    (_Float16)h1.x, (_Float16)h1.y, (_Float16)h1.z, (_Float16)h1.w};
        scv[cc] = sv;
        shv[cc] = hv;
    }

    f32x4 acc[4][4] = {};
    const char* Ab = (const char*)A;
    const char* Bb = (const char*)Wt;
    const half8 zerov = {0, 0, 0, 0, 0, 0, 0, 0};

#pragma unroll
    for (int ko = 0; ko < 4; ko++) {
        int kr = (ko + krot) & 3;
        int kb0 = kr * 128;
#pragma unroll
        for (int j = 0; j < 4; j++) {
            int sbase = wid * 256 + j * 64;
            int s = sbase + lane;
            int m = s >> 3;
            int c = (s & 7) ^ (m & 7);
            size_t go = (size_t)(row0 + m) * 512 + kb0 + c * 16;
            async16(Ab + go, (char*)smem + sbase * 16);
            size_t gob = (size_t)(col0 + m) * 512 + kb0 + c * 16;
            async16(Bb + gob, (char*)smem + 16384 + sbase * 16);
        }
        __syncthreads();
#pragma unroll
        for (int kc = 0; kc < 2; kc++) {
            half8 af[4], bf[4];
            half8 sv = scv[kr * 2 + kc];
            half8 hv = shv[kr * 2 + kc];
#pragma unroll
            for (int t = 0; t < 4; t++) {
                int ma = wm + t * 16 + lrow;
                int ca = kc * 4 + quad;
                half8 a = *(const half8*)((const char*)smem +
                                          (ma * 8 + (ca ^ (ma & 7))) * 16);
                af[t] = __builtin_elementwise_max(a * sv + hv, zerov);
                int mb = wn + t * 16 + lrow;
                bf[t] = *(const half8*)((const char*)smem + 16384 +
                                        (mb * 8 + (ca ^ (mb & 7))) * 16);
            }
#pragma unroll
            for (int i = 0; i < 4; i++)
#pragma unroll
                for (int j2 = 0; j2 < 4; j2++)
                    acc[i][j2] = __builtin_amdgcn_mfma_f32_16x16x32_f16(
                        af[i], bf[j2], acc[i][j2], 0, 0, 0);
        }
        if (ko < 3) __syncthreads();
    }

    GEMM_EPILOGUE
}

// ---------------------------------------------------------------------------
// Finalize BN2 from per-layer replicated stats (1 block; stats single-use,
// no re-zeroing needed -- per-layer buffers zeroed by the upfront memset).
// ---------------------------------------------------------------------------
__global__ __launch_bounds__(256) void bn_finalize(const float* __restrict__ stats,
                                                   const float* __restrict__ g,
                                                   const float* __restrict__ beta,
                                                   float* __restrict__ scsh,
                                                   int n) {
    int d = threadIdx.x;
    float s = 0.0f, sq = 0.0f;
#pragma unroll
    for (int r = 0; r < 8; r++) {
        s += stats[r * 512 + d];
        sq += stats[r * 512 + 256 + d];
    }
    float invn = 1.0f / (float)n;
    float mean = s * invn;
    float var = sq * invn - mean * mean;
    float inv = rsqrtf(var + 1e-5f);
    float scale = g[d] * inv;
    scsh[d] = scale;
    scsh[DIM + d] = beta[d] - mean * scale;
}

// ---------------------------------------------------------------------------
// Final BN apply (layer 4): no relu, fp32 out.  [round-6 form]
// ---------------------------------------------------------------------------
__global__ __launch_bounds__(256) void bn_apply_f(const _Float16* __restrict__ in,
                                                  float* __restrict__ outf,
                                                  const float* __restrict__ scsh) {
    size_t i = (size_t)blockIdx.x * 256 + threadIdx.x;
    int c4 = (int)(i & 63);
    float4 sc = ((const float4*)scsh)[c4];
    float4 sh = ((const float4*)(scsh + DIM))[c4];
    half4 v = ((const half4*)in)[i];
    float4 o;
    o.x = (float)v.x * sc.x + sh.x;
    o.y = (float)v.y * sc.y + sh.y;
    o.z = (float)v.z * sc.z + sh.z;
    o.w = (float)v.w * sc.w + sh.w;
    ((float4*)outf)[i] = o;
}

// ---------------------------------------------------------------------------
extern "C" void kernel_launch(void* const* d_in, const int* in_sizes, int n_in,
                              void* d_out, int out_size, void* d_ws, size_t ws_size,
                              hipStream_t stream) {
    (void)in_sizes; (void)n_in; (void)out_size; (void)ws_size;
    const float* x   = (const float*)d_in[0];
    const int*   src = (const int*)d_in[1];
    const int*   dst = (const int*)d_in[2];
    const float* W1  = (const float*)d_in[3];
    const float* b1  = (const float*)d_in[4];
    const float* g1  = (const float*)d_in[5];
    const float* bt1 = (const float*)d_in[6];
    const float* W2  = (const float*)d_in[7];
    const float* b2  = (const float*)d_in[8];
    const float* eps = (const float*)d_in[9];
    const float* bng = (const float*)d_in[10];
    const float* bnb = (const float*)d_in[11];
    float* out = (float*)d_out;

    const int N = N_NODES, E = N_EDGES, D = DIM;
    size_t NDp = (size_t)MPAD * D;

    _Float16* gin  = (_Float16*)d_ws;              // gather output / GEMM1 in
    _Float16* C1   = gin + NDp;                    // GEMM1 raw out (also xh @ l0)
    _Float16* C2   = C1 + NDp;                     // GEMM2 raw out
    _Float16* Wt   = C2 + NDp;                     // 10 * 256*256 fp16
    // [statsA(5 layers) | statsB(5 layers) | deg] contiguous -> one memset
    float* statsA  = (float*)(Wt + 10 * 65536);    // 5 * 8 * 512 f (BN1)
    float* statsB  = statsA + 5 * 4096;            // 5 * 8 * 512 f (BN2)
    int* deg       = (int*)(statsB + 5 * 4096);    // N (cursor)
    int* ptr       = deg + N;                      // N+1
    int* bsum      = ptr + N + 1;                  // 64
    int* srcbuf    = bsum + 64;                    // E
    float* scshB   = (float*)(srcbuf + E);         // 512 f (BN2 scale/shift)

    const int ELEM4_BLOCKS = N * D / 4 / 256;      // 12500
    const int NODE_BLOCKS  = (N + 3) / 4;          // 12500
    const int E_BLOCKS     = (E + 255) / 256;      // 1172
    const int SCAN_BLOCKS  = (N + 1023) / 1024;    // 49
    const dim3 GEMM_GRID(2, MPAD / 128);           // (2, 391)

    // ---- One-time per call: zero all per-layer stats + deg, CSR, prep ----
    hipMemsetAsync(statsA, 0, (size_t)(10 * 4096 + N) * sizeof(float), stream);
    hist_dst<<<E_BLOCKS, 256, 0, stream>>>(dst, deg, E);
    scan_blk<<<SCAN_BLOCKS, 1024, 0, stream>>>(deg, ptr, bsum, N);
    scan_add<<<SCAN_BLOCKS, 1024, 0, stream>>>(ptr, bsum, deg, N, E);
    scatter_src<<<E_BLOCKS, 256, 0, stream>>>(src, dst, deg, srcbuf, E);
    prep<<<160 + ELEM4_BLOCKS, 256, 0, stream>>>(W1, W2, Wt, x, C1);  // C1 = xh

    for (int l = 0; l < 5; l++) {
        float* stA = statsA + (size_t)l * 4096;
        float* stB = statsB + (size_t)l * 4096;

        // Gather (+ fused BN2-of-previous-layer via scshB for l>=1)
        if (l == 0)
            gather_h<<<NODE_BLOCKS, 256, 0, stream>>>(C1, ptr, srcbuf, gin, eps);
        else
            gather_bn<<<NODE_BLOCKS, 256, 0, stream>>>(C2, ptr, srcbuf, gin,
                                                       scshB, eps, l);

        // C1 = gin @ W1 + b1 (raw), fused BN1 stats -> statsA[l]
        gemm_f16<<<GEMM_GRID, 256, 0, stream>>>(
            gin, Wt + (size_t)l * 65536, b1 + (size_t)l * D, C1, stA, N);

        // C2 = relu(BN1(C1)) @ W2 + b2 (raw); BN1 finalized in-block from
        // statsA[l]; fused BN2 stats -> statsB[l]
        gemm_bn<<<GEMM_GRID, 256, 0, stream>>>(
            C1, Wt + (size_t)(5 + l) * 65536, b2 + (size_t)l * D, C2,
            stB, stA, g1 + (size_t)l * D, bt1 + (size_t)l * D, N);

        // BN2 scale/shift for the next gather (or final apply)
        bn_finalize<<<1, 256, 0, stream>>>(stB, bng + (size_t)l * D,
                                           bnb + (size_t)l * D, scshB, N);

        if (l == 4)
            bn_apply_f<<<ELEM4_BLOCKS, 256, 0, stream>>>(C2, out, scshB);
    }
}

// Round 10
// 636.317 us; speedup vs baseline: 2.0965x; 2.0965x over previous
//
#include <hip/hip_runtime.h>
#include <hip/hip_bf16.h>

#define N_NODES 50000
#define N_EDGES 300000
#define DIM 256
#define MPAD 50048   // 391 * 128

typedef __attribute__((ext_vector_type(8))) _Float16 half8;
typedef __attribute__((ext_vector_type(4))) _Float16 half4;
typedef __attribute__((ext_vector_type(4))) float f32x4;

__device__ __forceinline__ void async16(const void* g, void* l) {
    __builtin_amdgcn_global_load_lds(
        (const __attribute__((address_space(1))) unsigned int*)g,
        (__attribute__((address_space(3))) unsigned int*)l, 16, 0, 0);
}

// ---------------------------------------------------------------------------
// Per-thread BN finalize from 8 replicated stat buffers (d = tid, 256 wide).
// Used in-block ONLY by low-block-count consumers (gemm_bn: 782 blocks,
// ~12.5 MB L2). Round-7 measured: fusing into 12500-block consumers costs
// ~1 GB redundant reads -> regression. Round-9 measured: combining with
// __launch_bounds__(256,4) (forced spills) -> post-timing divergence; NO cap.
// ---------------------------------------------------------------------------
__device__ __forceinline__ void bn_finalize_thread(const float* __restrict__ st,
                                                   const float* __restrict__ g,
                                                   const float* __restrict__ beta,
                                                   float* scshL, int d, int n) {
    float s = 0.0f, sq = 0.0f;
#pragma unroll
    for (int r = 0; r < 8; r++) {
        s += st[r * 512 + d];
        sq += st[r * 512 + 256 + d];
    }
    float invn = 1.0f / (float)n;
    float mean = s * invn;
    float var = sq * invn - mean * mean;
    float inv = rsqrtf(var + 1e-5f);
    float scale = g[d] * inv;
    scshL[d] = scale;
    scshL[256 + d] = beta[d] - mean * scale;
}

// ---------------------------------------------------------------------------
// CSR build: histogram
// ---------------------------------------------------------------------------
__global__ __launch_bounds__(256) void hist_dst(const int* __restrict__ dst,
                                                int* __restrict__ deg, int E) {
    int e = blockIdx.x * blockDim.x + threadIdx.x;
    if (e < E) atomicAdd(&deg[dst[e]], 1);
}

// ---------------------------------------------------------------------------
// Hierarchical scan, step 1: per-block (1024) exclusive scan via wave shuffles.
// ---------------------------------------------------------------------------
__global__ __launch_bounds__(1024) void scan_blk(const int* __restrict__ deg,
                                                 int* __restrict__ ptr,
                                                 int* __restrict__ bsum, int n) {
    __shared__ int wsum[16];
    __shared__ int wpre[16];
    int tid = threadIdx.x;
    int i = blockIdx.x * 1024 + tid;
    int v = (i < n) ? deg[i] : 0;
    int lane = tid & 63, w = tid >> 6;
    int s = v;
#pragma unroll
    for (int off = 1; off < 64; off <<= 1) {
        int t = __shfl_up(s, off, 64);
        if (lane >= off) s += t;
    }
    if (lane == 63) wsum[w] = s;
    __syncthreads();
    if (tid < 16) {
        int acc = 0;
        for (int j = 0; j < tid; j++) acc += wsum[j];
        wpre[tid] = acc;
    }
    __syncthreads();
    int incl = s + wpre[w];
    if (i < n) ptr[i] = incl - v;
    if (tid == 1023) bsum[blockIdx.x] = incl;
}

// ---------------------------------------------------------------------------
// Scan step 2: each block redundantly reduces the block totals below it,
// adds offset, duplicates to cursor.
// ---------------------------------------------------------------------------
__global__ __launch_bounds__(1024) void scan_add(int* __restrict__ ptr,
                                                 const int* __restrict__ bsum,
                                                 int* __restrict__ cursor,
                                                 int n, int E) {
    __shared__ int soff;
    int tid = threadIdx.x;
    if (tid < 64) {
        int v = (tid < (int)blockIdx.x) ? bsum[tid] : 0;
#pragma unroll
        for (int off = 32; off > 0; off >>= 1) v += __shfl_down(v, off, 64);
        if (tid == 0) soff = v;
    }
    __syncthreads();
    int i = blockIdx.x * 1024 + tid;
    if (i < n) {
        int val = ptr[i] + soff;
        ptr[i] = val;
        cursor[i] = val;
    }
    if (i == n) ptr[n] = E;
}

// ---------------------------------------------------------------------------
// CSR build: counting-sort scatter
// ---------------------------------------------------------------------------
__global__ __launch_bounds__(256) void scatter_src(const int* __restrict__ src,
                                                   const int* __restrict__ dst,
                                                   int* __restrict__ cursor,
                                                   int* __restrict__ srcbuf, int E) {
    int e = blockIdx.x * blockDim.x + threadIdx.x;
    if (e < E) {
        int pos = atomicAdd(&cursor[dst[e]], 1);
        srcbuf[pos] = src[e];
    }
}

// ---------------------------------------------------------------------------
// Fused prep: blocks [0,160) transpose W (fp32->fp16 [N][K]); the rest
// convert x (fp32) -> fp16.
// ---------------------------------------------------------------------------
__global__ __launch_bounds__(256) void prep(const float* __restrict__ W1,
                                            const float* __restrict__ W2,
                                            _Float16* __restrict__ Wt,
                                            const float* __restrict__ x,
                                            _Float16* __restrict__ hb) {
    __shared__ float tile[64][65];
    int tid = threadIdx.x;
    if (blockIdx.x < 160) {
        int mat = blockIdx.x >> 4;
        int t = blockIdx.x & 15;
        int tr = t >> 2, tc = t & 3;
        const float* W = (mat < 5) ? (W1 + (size_t)mat * 65536)
                                   : (W2 + (size_t)(mat - 5) * 65536);
        int c = tid & 63, r0 = tid >> 6;
#pragma unroll 4
        for (int i = 0; i < 16; i++) {
            int r = r0 + i * 4;
            tile[r][c] = W[(size_t)(tr * 64 + r) * 256 + tc * 64 + c];
        }
        __syncthreads();
        _Float16* o = Wt + (size_t)mat * 65536;
#pragma unroll 4
        for (int i = 0; i < 16; i++) {
            int r = r0 + i * 4;
            o[(size_t)(tc * 64 + r) * 256 + tr * 64 + c] = (_Float16)tile[c][r];
        }
    } else {
        size_t i = (size_t)(blockIdx.x - 160) * 256 + tid;  // float4 index
        float4 v = ((const float4*)x)[i];
        half4 o;
        o.x = (_Float16)v.x; o.y = (_Float16)v.y;
        o.z = (_Float16)v.z; o.w = (_Float16)v.w;
        ((half4*)hb)[i] = o;
    }
}

// ---------------------------------------------------------------------------
// Layer-0 gather (fp16 x): z[n] = (1+eps)*xh[n] + sum relu(xh[src]).
// ---------------------------------------------------------------------------
__global__ __launch_bounds__(256) void gather_h(const _Float16* __restrict__ h,
                                                const int* __restrict__ ptr,
                                                const int* __restrict__ srcbuf,
                                                _Float16* __restrict__ z,
                                                const float* __restrict__ eps) {
    int node = blockIdx.x * 4 + (threadIdx.x >> 6);
    if (node >= N_NODES) return;
    int lane = threadIdx.x & 63;
    int beg = ptr[node], end = ptr[node + 1];
    float s = 1.0f + eps[0];
    half4 hv = ((const half4*)(h + (size_t)node * DIM))[lane];
    float a0 = (float)hv.x * s, a1 = (float)hv.y * s;
    float a2 = (float)hv.z * s, a3 = (float)hv.w * s;
    int e = beg;
    for (; e + 4 <= end; e += 4) {
        int s0 = srcbuf[e], s1 = srcbuf[e + 1], s2 = srcbuf[e + 2], s3 = srcbuf[e + 3];
        half4 v0 = ((const half4*)(h + (size_t)s0 * DIM))[lane];
        half4 v1 = ((const half4*)(h + (size_t)s1 * DIM))[lane];
        half4 v2 = ((const half4*)(h + (size_t)s2 * DIM))[lane];
        half4 v3 = ((const half4*)(h + (size_t)s3 * DIM))[lane];
        a0 += fmaxf((float)v0.x, 0.f) + fmaxf((float)v1.x, 0.f)
            + fmaxf((float)v2.x, 0.f) + fmaxf((float)v3.x, 0.f);
        a1 += fmaxf((float)v0.y, 0.f) + fmaxf((float)v1.y, 0.f)
            + fmaxf((float)v2.y, 0.f) + fmaxf((float)v3.y, 0.f);
        a2 += fmaxf((float)v0.z, 0.f) + fmaxf((float)v1.z, 0.f)
            + fmaxf((float)v2.z, 0.f) + fmaxf((float)v3.z, 0.f);
        a3 += fmaxf((float)v0.w, 0.f) + fmaxf((float)v1.w, 0.f)
            + fmaxf((float)v2.w, 0.f) + fmaxf((float)v3.w, 0.f);
    }
    for (; e < end; e++) {
        half4 v = ((const half4*)(h + (size_t)srcbuf[e] * DIM))[lane];
        a0 += fmaxf((float)v.x, 0.f); a1 += fmaxf((float)v.y, 0.f);
        a2 += fmaxf((float)v.z, 0.f); a3 += fmaxf((float)v.w, 0.f);
    }
    half4 o;
    o.x = (_Float16)a0; o.y = (_Float16)a1;
    o.z = (_Float16)a2; o.w = (_Float16)a3;
    ((half4*)(z + (size_t)node * DIM))[lane] = o;
}

// ---------------------------------------------------------------------------
// Layers 1..4 gather with fused BN2 (scale/shift precomputed by bn_finalize):
// h = relu(scale*C + shift) on the fly.  [round-6 form, measured best]
// ---------------------------------------------------------------------------
__global__ __launch_bounds__(256) void gather_bn(const _Float16* __restrict__ C,
                                                 const int* __restrict__ ptr,
                                                 const int* __restrict__ srcbuf,
                                                 _Float16* __restrict__ z,
                                                 const float* __restrict__ scsh,
                                                 const float* __restrict__ eps,
                                                 int l) {
    int node = blockIdx.x * 4 + (threadIdx.x >> 6);
    if (node >= N_NODES) return;
    int lane = threadIdx.x & 63;
    float4 sc = ((const float4*)scsh)[lane];
    float4 sh = ((const float4*)(scsh + DIM))[lane];
    int beg = ptr[node], end = ptr[node + 1];
    float s = 1.0f + eps[l];
    half4 hv = ((const half4*)(C + (size_t)node * DIM))[lane];
    float a0 = s * fmaxf((float)hv.x * sc.x + sh.x, 0.f);
    float a1 = s * fmaxf((float)hv.y * sc.y + sh.y, 0.f);
    float a2 = s * fmaxf((float)hv.z * sc.z + sh.z, 0.f);
    float a3 = s * fmaxf((float)hv.w * sc.w + sh.w, 0.f);
    int e = beg;
    for (; e + 4 <= end; e += 4) {
        int s0 = srcbuf[e], s1 = srcbuf[e + 1], s2 = srcbuf[e + 2], s3 = srcbuf[e + 3];
        half4 v0 = ((const half4*)(C + (size_t)s0 * DIM))[lane];
        half4 v1 = ((const half4*)(C + (size_t)s1 * DIM))[lane];
        half4 v2 = ((const half4*)(C + (size_t)s2 * DIM))[lane];
        half4 v3 = ((const half4*)(C + (size_t)s3 * DIM))[lane];
        a0 += fmaxf((float)v0.x * sc.x + sh.x, 0.f) + fmaxf((float)v1.x * sc.x + sh.x, 0.f)
            + fmaxf((float)v2.x * sc.x + sh.x, 0.f) + fmaxf((float)v3.x * sc.x + sh.x, 0.f);
        a1 += fmaxf((float)v0.y * sc.y + sh.y, 0.f) + fmaxf((float)v1.y * sc.y + sh.y, 0.f)
            + fmaxf((float)v2.y * sc.y + sh.y, 0.f) + fmaxf((float)v3.y * sc.y + sh.y, 0.f);
        a2 += fmaxf((float)v0.z * sc.z + sh.z, 0.f) + fmaxf((float)v1.z * sc.z + sh.z, 0.f)
            + fmaxf((float)v2.z * sc.z + sh.z, 0.f) + fmaxf((float)v3.z * sc.z + sh.z, 0.f);
        a3 += fmaxf((float)v0.w * sc.w + sh.w, 0.f) + fmaxf((float)v1.w * sc.w + sh.w, 0.f)
            + fmaxf((float)v2.w * sc.w + sh.w, 0.f) + fmaxf((float)v3.w * sc.w + sh.w, 0.f);
    }
    for (; e < end; e++) {
        half4 v = ((const half4*)(C + (size_t)srcbuf[e] * DIM))[lane];
        a0 += fmaxf((float)v.x * sc.x + sh.x, 0.f);
        a1 += fmaxf((float)v.y * sc.y + sh.y, 0.f);
        a2 += fmaxf((float)v.z * sc.z + sh.z, 0.f);
        a3 += fmaxf((float)v.w * sc.w + sh.w, 0.f);
    }
    half4 o;
    o.x = (_Float16)a0; o.y = (_Float16)a1;
    o.z = (_Float16)a2; o.w = (_Float16)a3;
    ((half4*)(z + (size_t)node * DIM))[lane] = o;
}

// ===========================================================================
// GEMM: 128x128 tile, BK=64 (4 K-steps, STATIC order), XOR-swizzled LDS
// staging. NO __launch_bounds__ min-wave arg (round-9: the 128-VGPR cap on
// gemm_bn's ~180-reg live set forced spills and produced post-timing
// divergence under graph replay). 108-130 VGPR -> 4 waves/SIMD naturally;
// LDS 35840/37888 B -> 4 blocks/CU.
// ===========================================================================
#define GEMM_EPILOGUE                                                        \
    __syncthreads();                                                         \
    float* colsum = (float*)((char*)smem + 34816);                           \
    float* colsq = colsum + 128;                                             \
    if (tid < 128) { colsum[tid] = 0.0f; colsq[tid] = 0.0f; }                \
    _Float16* Cs = (_Float16*)smem;                                          \
    float bcol[4];                                                           \
    _Pragma("unroll")                                                        \
    for (int j = 0; j < 4; j++) bcol[j] = bias[col0 + wn + j * 16 + lrow];   \
    float csum[4] = {0.f, 0.f, 0.f, 0.f};                                    \
    float csq[4] = {0.f, 0.f, 0.f, 0.f};                                     \
    _Pragma("unroll")                                                        \
    for (int i = 0; i < 4; i++) {                                            \
        int rl = wm + i * 16 + quad * 4;                                     \
        _Pragma("unroll")                                                    \
        for (int j = 0; j < 4; j++) {                                        \
            int cl = wn + j * 16 + lrow;                                     \
            _Pragma("unroll")                                                \
            for (int r = 0; r < 4; r++) {                                    \
                float v = acc[i][j][r] + bcol[j];                            \
                Cs[(rl + r) * 136 + cl] = (_Float16)v;                       \
                if (row0 + rl + r < M) { csum[j] += v; csq[j] += v * v; }    \
            }                                                                \
        }                                                                    \
    }                                                                        \
    __syncthreads();                                                         \
    {                                                                        \
        int rgrp = lane >> 4, ch = lane & 15;                                \
        _Pragma("unroll")                                                    \
        for (int it = 0; it < 8; it++) {                                     \
            int row = wid * 32 + it * 4 + rgrp;                              \
            uint4 vv = *(const uint4*)(Cs + row * 136 + ch * 8);             \
            *(uint4*)(C + (size_t)(row0 + row) * DIM + col0 + ch * 8) = vv;  \
        }                                                                    \
    }                                                                        \
    _Pragma("unroll")                                                        \
    for (int j = 0; j < 4; j++) {                                            \
        atomicAdd(&colsum[wn + j * 16 + lrow], csum[j]);                     \
        atomicAdd(&colsq[wn + j * 16 + lrow], csq[j]);                       \
    }                                                                        \
    __syncthreads();                                                         \
    if (tid < 128) {                                                         \
        float* st = stats + (blockIdx.y & 7) * 512;                          \
        atomicAdd(&st[col0 + tid], colsum[tid]);                             \
        atomicAdd(&st[DIM + col0 + tid], colsq[tid]);                        \
    }

__global__ __launch_bounds__(256) void gemm_f16(const _Float16* __restrict__ A,
                                                const _Float16* __restrict__ Wt,
                                                const float* __restrict__ bias,
                                                _Float16* __restrict__ C,
                                                float* __restrict__ stats,
                                                int M) {
    __shared__ uint4 smem[2240];  // 35840 B: A 16K | B 16K (epi: 34816+1024)

    int tid = threadIdx.x;
    int wid = tid >> 6, lane = tid & 63;
    int quad = lane >> 4, lrow = lane & 15;
    int row0 = blockIdx.y * 128, col0 = blockIdx.x * 128;
    int wm = (wid & 1) * 64, wn = (wid >> 1) * 64;

    f32x4 acc[4][4] = {};
    const char* Ab = (const char*)A;
    const char* Bb = (const char*)Wt;

#pragma unroll
    for (int ko = 0; ko < 4; ko++) {
        int kb0 = ko * 128;  // byte offset of this K-quarter within a 512B row
#pragma unroll
        for (int j = 0; j < 4; j++) {
            int sbase = wid * 256 + j * 64;   // 16B-slot base (wave-uniform)
            int s = sbase + lane;
            int m = s >> 3;                   // row 0..127
            int c = (s & 7) ^ (m & 7);        // swizzled slot 0..7
            size_t go = (size_t)(row0 + m) * 512 + kb0 + c * 16;
            async16(Ab + go, (char*)smem + sbase * 16);
            size_t gob = (size_t)(col0 + m) * 512 + kb0 + c * 16;
            async16(Bb + gob, (char*)smem + 16384 + sbase * 16);
        }
        __syncthreads();
#pragma unroll
        for (int kc = 0; kc < 2; kc++) {
            half8 af[4], bf[4];
#pragma unroll
            for (int t = 0; t < 4; t++) {
                int ma = wm + t * 16 + lrow;
                int ca = kc * 4 + quad;       // 0..7
                af[t] = *(const half8*)((const char*)smem +
                                        (ma * 8 + (ca ^ (ma & 7))) * 16);
                int mb = wn + t * 16 + lrow;
                bf[t] = *(const half8*)((const char*)smem + 16384 +
                                        (mb * 8 + (ca ^ (mb & 7))) * 16);
            }
#pragma unroll
            for (int i = 0; i < 4; i++)
#pragma unroll
                for (int j2 = 0; j2 < 4; j2++)
                    acc[i][j2] = __builtin_amdgcn_mfma_f32_16x16x32_f16(
                        af[i], bf[j2], acc[i][j2], 0, 0, 0);
        }
        if (ko < 3) __syncthreads();
    }

    GEMM_EPILOGUE
}

// Same GEMM; BN1 finalized IN-BLOCK from statsIn (782 blocks x 16KB = cheap)
// into LDS, applied to the A-operand as scale/shift+ReLU (STATIC ko index).
__global__ __launch_bounds__(256) void gemm_bn(const _Float16* __restrict__ A,
                                               const _Float16* __restrict__ Wt,
                                               const float* __restrict__ bias,
                                               _Float16* __restrict__ C,
                                               float* __restrict__ stats,
                                               const float* __restrict__ statsIn,
                                               const float* __restrict__ gamma1,
                                               const float* __restrict__ beta1,
                                               int M) {
    __shared__ uint4 smem[2368];  // 35840 B staging/epi + 2048 B scshL

    int tid = threadIdx.x;
    int wid = tid >> 6, lane = tid & 63;
    int quad = lane >> 4, lrow = lane & 15;
    int row0 = blockIdx.y * 128, col0 = blockIdx.x * 128;
    int wm = (wid & 1) * 64, wn = (wid >> 1) * 64;

    // In-block BN1 finalize -> LDS (region disjoint from staging/epilogue)
    float* scshL = (float*)((char*)smem + 35840);
    bn_finalize_thread(statsIn, gamma1, beta1, scshL, tid, M);
    __syncthreads();

    // Per-lane BN1 scale/shift fragments for all 8 k-chunks (fp16, regs)
    half8 scv[8], shv[8];
#pragma unroll
    for (int cc = 0; cc < 8; cc++) {
        int kk = cc * 32 + quad * 8;
        float4 s0 = *(const float4*)(scshL + kk);
        float4 s1 = *(const float4*)(scshL + kk + 4);
        float4 h0 = *(const float4*)(scshL + DIM + kk);
        float4 h1 = *(const float4*)(scshL + DIM + kk + 4);
        half8 sv = {(_Float16)s0.x, (_Float16)s0.y, (_Float16)s0.z, (_Float16)s0.w,
                    (_Float16)s1.x, (_Float16)s1.y, (_Float16)s1.z, (_Float16)s1.w};
        half8 hv = {(_Float16)h0.x, (_Float16)h0.y, (_Float16)h0.z, (_Float16)h0.w,
                    (_Float16)h1.x, (_Float16)h1.y, (_Float16)h1.z, (_Float16)h1.w};
        scv[cc] = sv;
        shv[cc] = hv;
    }

    f32x4 acc[4][4] = {};
    const char* Ab = (const char*)A;
    const char* Bb = (const char*)Wt;
    const half8 zerov = {0, 0, 0, 0, 0, 0, 0, 0};

#pragma unroll
    for (int ko = 0; ko < 4; ko++) {
        int kb0 = ko * 128;
#pragma unroll
        for (int j = 0; j < 4; j++) {
            int sbase = wid * 256 + j * 64;
            int s = sbase + lane;
            int m = s >> 3;
            int c = (s & 7) ^ (m & 7);
            size_t go = (size_t)(row0 + m) * 512 + kb0 + c * 16;
            async16(Ab + go, (char*)smem + sbase * 16);
            size_t gob = (size_t)(col0 + m) * 512 + kb0 + c * 16;
            async16(Bb + gob, (char*)smem + 16384 + sbase * 16);
        }
        __syncthreads();
#pragma unroll
        for (int kc = 0; kc < 2; kc++) {
            half8 af[4], bf[4];
            half8 sv = scv[ko * 2 + kc];
            half8 hv = shv[ko * 2 + kc];
#pragma unroll
            for (int t = 0; t < 4; t++) {
                int ma = wm + t * 16 + lrow;
                int ca = kc * 4 + quad;
                half8 a = *(const half8*)((const char*)smem +
                                          (ma * 8 + (ca ^ (ma & 7))) * 16);
                af[t] = __builtin_elementwise_max(a * sv + hv, zerov);
                int mb = wn + t * 16 + lrow;
                bf[t] = *(const half8*)((const char*)smem + 16384 +
                                        (mb * 8 + (ca ^ (mb & 7))) * 16);
            }
#pragma unroll
            for (int i = 0; i < 4; i++)
#pragma unroll
                for (int j2 = 0; j2 < 4; j2++)
                    acc[i][j2] = __builtin_amdgcn_mfma_f32_16x16x32_f16(
                        af[i], bf[j2], acc[i][j2], 0, 0, 0);
        }
        if (ko < 3) __syncthreads();
    }

    GEMM_EPILOGUE
}

// ---------------------------------------------------------------------------
// Finalize BN2 from per-layer replicated stats (1 block; stats single-use,
// per-layer buffers zeroed by the upfront memset).
// ---------------------------------------------------------------------------
__global__ __launch_bounds__(256) void bn_finalize(const float* __restrict__ stats,
                                                   const float* __restrict__ g,
                                                   const float* __restrict__ beta,
                                                   float* __restrict__ scsh,
                                                   int n) {
    int d = threadIdx.x;
    float s = 0.0f, sq = 0.0f;
#pragma unroll
    for (int r = 0; r < 8; r++) {
        s += stats[r * 512 + d];
        sq += stats[r * 512 + 256 + d];
    }
    float invn = 1.0f / (float)n;
    float mean = s * invn;
    float var = sq * invn - mean * mean;
    float inv = rsqrtf(var + 1e-5f);
    float scale = g[d] * inv;
    scsh[d] = scale;
    scsh[DIM + d] = beta[d] - mean * scale;
}

// ---------------------------------------------------------------------------
// Final BN apply (layer 4): no relu, fp32 out.  [round-6 form]
// ---------------------------------------------------------------------------
__global__ __launch_bounds__(256) void bn_apply_f(const _Float16* __restrict__ in,
                                                  float* __restrict__ outf,
                                                  const float* __restrict__ scsh) {
    size_t i = (size_t)blockIdx.x * 256 + threadIdx.x;
    int c4 = (int)(i & 63);
    float4 sc = ((const float4*)scsh)[c4];
    float4 sh = ((const float4*)(scsh + DIM))[c4];
    half4 v = ((const half4*)in)[i];
    float4 o;
    o.x = (float)v.x * sc.x + sh.x;
    o.y = (float)v.y * sc.y + sh.y;
    o.z = (float)v.z * sc.z + sh.z;
    o.w = (float)v.w * sc.w + sh.w;
    ((float4*)outf)[i] = o;
}

// ---------------------------------------------------------------------------
extern "C" void kernel_launch(void* const* d_in, const int* in_sizes, int n_in,
                              void* d_out, int out_size, void* d_ws, size_t ws_size,
                              hipStream_t stream) {
    (void)in_sizes; (void)n_in; (void)out_size; (void)ws_size;
    const float* x   = (const float*)d_in[0];
    const int*   src = (const int*)d_in[1];
    const int*   dst = (const int*)d_in[2];
    const float* W1  = (const float*)d_in[3];
    const float* b1  = (const float*)d_in[4];
    const float* g1  = (const float*)d_in[5];
    const float* bt1 = (const float*)d_in[6];
    const float* W2  = (const float*)d_in[7];
    const float* b2  = (const float*)d_in[8];
    const float* eps = (const float*)d_in[9];
    const float* bng = (const float*)d_in[10];
    const float* bnb = (const float*)d_in[11];
    float* out = (float*)d_out;

    const int N = N_NODES, E = N_EDGES, D = DIM;
    size_t NDp = (size_t)MPAD * D;

    _Float16* gin  = (_Float16*)d_ws;              // gather output / GEMM1 in
    _Float16* C1   = gin + NDp;                    // GEMM1 raw out (also xh @ l0)
    _Float16* C2   = C1 + NDp;                     // GEMM2 raw out
    _Float16* Wt   = C2 + NDp;                     // 10 * 256*256 fp16
    // [statsA(5 layers) | statsB(5 layers) | deg] contiguous -> one memset
    float* statsA  = (float*)(Wt + 10 * 65536);    // 5 * 8 * 512 f (BN1)
    float* statsB  = statsA + 5 * 4096;            // 5 * 8 * 512 f (BN2)
    int* deg       = (int*)(statsB + 5 * 4096);    // N (cursor)
    int* ptr       = deg + N;                      // N+1
    int* bsum      = ptr + N + 1;                  // 64
    int* srcbuf    = bsum + 64;                    // E
    float* scshB   = (float*)(srcbuf + E);         // 512 f (BN2 scale/shift)

    const int ELEM4_BLOCKS = N * D / 4 / 256;      // 12500
    const int NODE_BLOCKS  = (N + 3) / 4;          // 12500
    const int E_BLOCKS     = (E + 255) / 256;      // 1172
    const int SCAN_BLOCKS  = (N + 1023) / 1024;    // 49
    const dim3 GEMM_GRID(2, MPAD / 128);           // (2, 391)

    // ---- One-time per call: zero all per-layer stats + deg, CSR, prep ----
    hipMemsetAsync(statsA, 0, (size_t)(10 * 4096 + N) * sizeof(float), stream);
    hist_dst<<<E_BLOCKS, 256, 0, stream>>>(dst, deg, E);
    scan_blk<<<SCAN_BLOCKS, 1024, 0, stream>>>(deg, ptr, bsum, N);
    scan_add<<<SCAN_BLOCKS, 1024, 0, stream>>>(ptr, bsum, deg, N, E);
    scatter_src<<<E_BLOCKS, 256, 0, stream>>>(src, dst, deg, srcbuf, E);
    prep<<<160 + ELEM4_BLOCKS, 256, 0, stream>>>(W1, W2, Wt, x, C1);  // C1 = xh

    for (int l = 0; l < 5; l++) {
        float* stA = statsA + (size_t)l * 4096;
        float* stB = statsB + (size_t)l * 4096;

        // Gather (+ fused BN2-of-previous-layer via scshB for l>=1)
        if (l == 0)
            gather_h<<<NODE_BLOCKS, 256, 0, stream>>>(C1, ptr, srcbuf, gin, eps);
        else
            gather_bn<<<NODE_BLOCKS, 256, 0, stream>>>(C2, ptr, srcbuf, gin,
                                                       scshB, eps, l);

        // C1 = gin @ W1 + b1 (raw), fused BN1 stats -> statsA[l]
        gemm_f16<<<GEMM_GRID, 256, 0, stream>>>(
            gin, Wt + (size_t)l * 65536, b1 + (size_t)l * D, C1, stA, N);

        // C2 = relu(BN1(C1)) @ W2 + b2 (raw); BN1 finalized in-block from
        // statsA[l]; fused BN2 stats -> statsB[l]
        gemm_bn<<<GEMM_GRID, 256, 0, stream>>>(
            C1, Wt + (size_t)(5 + l) * 65536, b2 + (size_t)l * D, C2,
            stB, stA, g1 + (size_t)l * D, bt1 + (size_t)l * D, N);

        // BN2 scale/shift for the next gather (or final apply)
        bn_finalize<<<1, 256, 0, stream>>>(stB, bng + (size_t)l * D,
                                           bnb + (size_t)l * D, scshB, N);

        if (l == 4)
            bn_apply_f<<<ELEM4_BLOCKS, 256, 0, stream>>>(C2, out, scshB);
    }
}

// Round 12
// 626.064 us; speedup vs baseline: 2.1308x; 1.0164x over previous
//
#include <hip/hip_runtime.h>
#include <hip/hip_bf16.h>

#define N_NODES 50000
#define N_EDGES 300000
#define DIM 256
#define MPAD 50048   // 391 * 128

typedef __attribute__((ext_vector_type(8))) _Float16 half8;
typedef __attribute__((ext_vector_type(4))) _Float16 half4;
typedef __attribute__((ext_vector_type(4))) float f32x4;

__device__ __forceinline__ void async16(const void* g, void* l) {
    __builtin_amdgcn_global_load_lds(
        (const __attribute__((address_space(1))) unsigned int*)g,
        (__attribute__((address_space(3))) unsigned int*)l, 16, 0, 0);
}

// ---------------------------------------------------------------------------
// Per-thread BN finalize from 8 replicated stat buffers (d = tid, 256 wide).
// In-block use ONLY for low-block-count consumers (gemm_bn: 782 blocks).
// r7: fusing into 12500-block consumers -> ~1GB redundant reads, regression.
// r9: __launch_bounds__(256,4) forced spills -> replay divergence; NO cap.
// ---------------------------------------------------------------------------
__device__ __forceinline__ void bn_finalize_thread(const float* __restrict__ st,
                                                   const float* __restrict__ g,
                                                   const float* __restrict__ beta,
                                                   float* scshL, int d, int n) {
    float s = 0.0f, sq = 0.0f;
#pragma unroll
    for (int r = 0; r < 8; r++) {
        s += st[r * 512 + d];
        sq += st[r * 512 + 256 + d];
    }
    float invn = 1.0f / (float)n;
    float mean = s * invn;
    float var = sq * invn - mean * mean;
    float inv = rsqrtf(var + 1e-5f);
    float scale = g[d] * inv;
    scshL[d] = scale;
    scshL[256 + d] = beta[d] - mean * scale;
}

// ---------------------------------------------------------------------------
// CSR build: histogram
// ---------------------------------------------------------------------------
__global__ __launch_bounds__(256) void hist_dst(const int* __restrict__ dst,
                                                int* __restrict__ deg, int E) {
    int e = blockIdx.x * blockDim.x + threadIdx.x;
    if (e < E) atomicAdd(&deg[dst[e]], 1);
}

// ---------------------------------------------------------------------------
// Hierarchical scan, step 1: per-block (1024) exclusive scan via wave shuffles.
// ---------------------------------------------------------------------------
__global__ __launch_bounds__(1024) void scan_blk(const int* __restrict__ deg,
                                                 int* __restrict__ ptr,
                                                 int* __restrict__ bsum, int n) {
    __shared__ int wsum[16];
    __shared__ int wpre[16];
    int tid = threadIdx.x;
    int i = blockIdx.x * 1024 + tid;
    int v = (i < n) ? deg[i] : 0;
    int lane = tid & 63, w = tid >> 6;
    int s = v;
#pragma unroll
    for (int off = 1; off < 64; off <<= 1) {
        int t = __shfl_up(s, off, 64);
        if (lane >= off) s += t;
    }
    if (lane == 63) wsum[w] = s;
    __syncthreads();
    if (tid < 16) {
        int acc = 0;
        for (int j = 0; j < tid; j++) acc += wsum[j];
        wpre[tid] = acc;
    }
    __syncthreads();
    int incl = s + wpre[w];
    if (i < n) ptr[i] = incl - v;
    if (tid == 1023) bsum[blockIdx.x] = incl;
}

// ---------------------------------------------------------------------------
// Scan step 2: each block redundantly reduces the block totals below it,
// adds offset, duplicates to cursor.
// ---------------------------------------------------------------------------
__global__ __launch_bounds__(1024) void scan_add(int* __restrict__ ptr,
                                                 const int* __restrict__ bsum,
                                                 int* __restrict__ cursor,
                                                 int n, int E) {
    __shared__ int soff;
    int tid = threadIdx.x;
    if (tid < 64) {
        int v = (tid < (int)blockIdx.x) ? bsum[tid] : 0;
#pragma unroll
        for (int off = 32; off > 0; off >>= 1) v += __shfl_down(v, off, 64);
        if (tid == 0) soff = v;
    }
    __syncthreads();
    int i = blockIdx.x * 1024 + tid;
    if (i < n) {
        int val = ptr[i] + soff;
        ptr[i] = val;
        cursor[i] = val;
    }
    if (i == n) ptr[n] = E;
}

// ---------------------------------------------------------------------------
// CSR build: counting-sort scatter
// ---------------------------------------------------------------------------
__global__ __launch_bounds__(256) void scatter_src(const int* __restrict__ src,
                                                   const int* __restrict__ dst,
                                                   int* __restrict__ cursor,
                                                   int* __restrict__ srcbuf, int E) {
    int e = blockIdx.x * blockDim.x + threadIdx.x;
    if (e < E) {
        int pos = atomicAdd(&cursor[dst[e]], 1);
        srcbuf[pos] = src[e];
    }
}

// ---------------------------------------------------------------------------
// Fused prep: blocks [0,160) transpose W (fp32->fp16 [N][K]); the rest
// convert x (fp32) -> fp16.
// ---------------------------------------------------------------------------
__global__ __launch_bounds__(256) void prep(const float* __restrict__ W1,
                                            const float* __restrict__ W2,
                                            _Float16* __restrict__ Wt,
                                            const float* __restrict__ x,
                                            _Float16* __restrict__ hb) {
    __shared__ float tile[64][65];
    int tid = threadIdx.x;
    if (blockIdx.x < 160) {
        int mat = blockIdx.x >> 4;
        int t = blockIdx.x & 15;
        int tr = t >> 2, tc = t & 3;
        const float* W = (mat < 5) ? (W1 + (size_t)mat * 65536)
                                   : (W2 + (size_t)(mat - 5) * 65536);
        int c = tid & 63, r0 = tid >> 6;
#pragma unroll 4
        for (int i = 0; i < 16; i++) {
            int r = r0 + i * 4;
            tile[r][c] = W[(size_t)(tr * 64 + r) * 256 + tc * 64 + c];
        }
        __syncthreads();
        _Float16* o = Wt + (size_t)mat * 65536;
#pragma unroll 4
        for (int i = 0; i < 16; i++) {
            int r = r0 + i * 4;
            o[(size_t)(tc * 64 + r) * 256 + tr * 64 + c] = (_Float16)tile[c][r];
        }
    } else {
        size_t i = (size_t)(blockIdx.x - 160) * 256 + tid;  // float4 index
        float4 v = ((const float4*)x)[i];
        half4 o;
        o.x = (_Float16)v.x; o.y = (_Float16)v.y;
        o.z = (_Float16)v.z; o.w = (_Float16)v.w;
        ((half4*)hb)[i] = o;
    }
}

// ---------------------------------------------------------------------------
// Layer-0 gather (fp16 x): z[n] = (1+eps)*xh[n] + sum relu(xh[src]).
// ---------------------------------------------------------------------------
__global__ __launch_bounds__(256) void gather_h(const _Float16* __restrict__ h,
                                                const int* __restrict__ ptr,
                                                const int* __restrict__ srcbuf,
                                                _Float16* __restrict__ z,
                                                const float* __restrict__ eps) {
    int node = blockIdx.x * 4 + (threadIdx.x >> 6);
    if (node >= N_NODES) return;
    int lane = threadIdx.x & 63;
    int beg = ptr[node], end = ptr[node + 1];
    float s = 1.0f + eps[0];
    half4 hv = ((const half4*)(h + (size_t)node * DIM))[lane];
    float a0 = (float)hv.x * s, a1 = (float)hv.y * s;
    float a2 = (float)hv.z * s, a3 = (float)hv.w * s;
    int e = beg;
    for (; e + 4 <= end; e += 4) {
        int s0 = srcbuf[e], s1 = srcbuf[e + 1], s2 = srcbuf[e + 2], s3 = srcbuf[e + 3];
        half4 v0 = ((const half4*)(h + (size_t)s0 * DIM))[lane];
        half4 v1 = ((const half4*)(h + (size_t)s1 * DIM))[lane];
        half4 v2 = ((const half4*)(h + (size_t)s2 * DIM))[lane];
        half4 v3 = ((const half4*)(h + (size_t)s3 * DIM))[lane];
        a0 += fmaxf((float)v0.x, 0.f) + fmaxf((float)v1.x, 0.f)
            + fmaxf((float)v2.x, 0.f) + fmaxf((float)v3.x, 0.f);
        a1 += fmaxf((float)v0.y, 0.f) + fmaxf((float)v1.y, 0.f)
            + fmaxf((float)v2.y, 0.f) + fmaxf((float)v3.y, 0.f);
        a2 += fmaxf((float)v0.z, 0.f) + fmaxf((float)v1.z, 0.f)
            + fmaxf((float)v2.z, 0.f) + fmaxf((float)v3.z, 0.f);
        a3 += fmaxf((float)v0.w, 0.f) + fmaxf((float)v1.w, 0.f)
            + fmaxf((float)v2.w, 0.f) + fmaxf((float)v3.w, 0.f);
    }
    for (; e < end; e++) {
        half4 v = ((const half4*)(h + (size_t)srcbuf[e] * DIM))[lane];
        a0 += fmaxf((float)v.x, 0.f); a1 += fmaxf((float)v.y, 0.f);
        a2 += fmaxf((float)v.z, 0.f); a3 += fmaxf((float)v.w, 0.f);
    }
    half4 o;
    o.x = (_Float16)a0; o.y = (_Float16)a1;
    o.z = (_Float16)a2; o.w = (_Float16)a3;
    ((half4*)(z + (size_t)node * DIM))[lane] = o;
}

// ---------------------------------------------------------------------------
// Layers 1..4 gather with fused BN2 (scale/shift precomputed by bn_finalize):
// h = relu(scale*C + shift) on the fly.  [round-6 form, measured best]
// ---------------------------------------------------------------------------
__global__ __launch_bounds__(256) void gather_bn(const _Float16* __restrict__ C,
                                                 const int* __restrict__ ptr,
                                                 const int* __restrict__ srcbuf,
                                                 _Float16* __restrict__ z,
                                                 const float* __restrict__ scsh,
                                                 const float* __restrict__ eps,
                                                 int l) {
    int node = blockIdx.x * 4 + (threadIdx.x >> 6);
    if (node >= N_NODES) return;
    int lane = threadIdx.x & 63;
    float4 sc = ((const float4*)scsh)[lane];
    float4 sh = ((const float4*)(scsh + DIM))[lane];
    int beg = ptr[node], end = ptr[node + 1];
    float s = 1.0f + eps[l];
    half4 hv = ((const half4*)(C + (size_t)node * DIM))[lane];
    float a0 = s * fmaxf((float)hv.x * sc.x + sh.x, 0.f);
    float a1 = s * fmaxf((float)hv.y * sc.y + sh.y, 0.f);
    float a2 = s * fmaxf((float)hv.z * sc.z + sh.z, 0.f);
    float a3 = s * fmaxf((float)hv.w * sc.w + sh.w, 0.f);
    int e = beg;
    for (; e + 4 <= end; e += 4) {
        int s0 = srcbuf[e], s1 = srcbuf[e + 1], s2 = srcbuf[e + 2], s3 = srcbuf[e + 3];
        half4 v0 = ((const half4*)(C + (size_t)s0 * DIM))[lane];
        half4 v1 = ((const half4*)(C + (size_t)s1 * DIM))[lane];
        half4 v2 = ((const half4*)(C + (size_t)s2 * DIM))[lane];
        half4 v3 = ((const half4*)(C + (size_t)s3 * DIM))[lane];
        a0 += fmaxf((float)v0.x * sc.x + sh.x, 0.f) + fmaxf((float)v1.x * sc.x + sh.x, 0.f)
            + fmaxf((float)v2.x * sc.x + sh.x, 0.f) + fmaxf((float)v3.x * sc.x + sh.x, 0.f);
        a1 += fmaxf((float)v0.y * sc.y + sh.y, 0.f) + fmaxf((float)v1.y * sc.y + sh.y, 0.f)
            + fmaxf((float)v2.y * sc.y + sh.y, 0.f) + fmaxf((float)v3.y * sc.y + sh.y, 0.f);
        a2 += fmaxf((float)v0.z * sc.z + sh.z, 0.f) + fmaxf((float)v1.z * sc.z + sh.z, 0.f)
            + fmaxf((float)v2.z * sc.z + sh.z, 0.f) + fmaxf((float)v3.z * sc.z + sh.z, 0.f);
        a3 += fmaxf((float)v0.w * sc.w + sh.w, 0.f) + fmaxf((float)v1.w * sc.w + sh.w, 0.f)
            + fmaxf((float)v2.w * sc.w + sh.w, 0.f) + fmaxf((float)v3.w * sc.w + sh.w, 0.f);
    }
    for (; e < end; e++) {
        half4 v = ((const half4*)(C + (size_t)srcbuf[e] * DIM))[lane];
        a0 += fmaxf((float)v.x * sc.x + sh.x, 0.f);
        a1 += fmaxf((float)v.y * sc.y + sh.y, 0.f);
        a2 += fmaxf((float)v.z * sc.z + sh.z, 0.f);
        a3 += fmaxf((float)v.w * sc.w + sh.w, 0.f);
    }
    half4 o;
    o.x = (_Float16)a0; o.y = (_Float16)a1;
    o.z = (_Float16)a2; o.w = (_Float16)a3;
    ((half4*)(z + (size_t)node * DIM))[lane] = o;
}

// ===========================================================================
// GEMM: 128x128 tile, BK=32 (8 K-steps = one MFMA K-slice each), DOUBLE-
// BUFFERED LDS staging in the same 32 KB footprint (buf{0,1} x (A 8K|B 8K))
// -> LDS stays 35840/37888 B, 4 blocks/CU preserved.  2-phase schedule:
// issue next step's global_load_lds BEFORE computing the current buffer;
// ONE __syncthreads() per step (its compiler-emitted vmcnt drain lands the
// in-flight loads).  Loop fully unrolled: all buffer offsets compile-time
// (rule #20).  K-summation order identical to BK=64 (8 ascending K=32
// slices) -> bitwise-same accumulation.
// Swizzle at 4 slots/row: write c=(s&3)^(m&3), read slot=quad^(ma&3) --
// same involution both sides, linear global_load_lds dest (rule #21).
// ===========================================================================
#define GEMM_EPILOGUE                                                        \
    __syncthreads();                                                         \
    float* colsum = (float*)((char*)smem + 34816);                           \
    float* colsq = colsum + 128;                                             \
    if (tid < 128) { colsum[tid] = 0.0f; colsq[tid] = 0.0f; }                \
    _Float16* Cs = (_Float16*)smem;                                          \
    float bcol[4];                                                           \
    _Pragma("unroll")                                                        \
    for (int j = 0; j < 4; j++) bcol[j] = bias[col0 + wn + j * 16 + lrow];   \
    float csum[4] = {0.f, 0.f, 0.f, 0.f};                                    \
    float csq[4] = {0.f, 0.f, 0.f, 0.f};                                     \
    _Pragma("unroll")                                                        \
    for (int i = 0; i < 4; i++) {                                            \
        int rl = wm + i * 16 + quad * 4;                                     \
        _Pragma("unroll")                                                    \
        for (int j = 0; j < 4; j++) {                                        \
            int cl = wn + j * 16 + lrow;                                     \
            _Pragma("unroll")                                                \
            for (int r = 0; r < 4; r++) {                                    \
                float v = acc[i][j][r] + bcol[j];                            \
                Cs[(rl + r) * 136 + cl] = (_Float16)v;                       \
                if (row0 + rl + r < M) { csum[j] += v; csq[j] += v * v; }    \
            }                                                                \
        }                                                                    \
    }                                                                        \
    __syncthreads();                                                         \
    {                                                                        \
        int rgrp = lane >> 4, ch = lane & 15;                                \
        _Pragma("unroll")                                                    \
        for (int it = 0; it < 8; it++) {                                     \
            int row = wid * 32 + it * 4 + rgrp;                              \
            uint4 vv = *(const uint4*)(Cs + row * 136 + ch * 8);             \
            *(uint4*)(C + (size_t)(row0 + row) * DIM + col0 + ch * 8) = vv;  \
        }                                                                    \
    }                                                                        \
    _Pragma("unroll")                                                        \
    for (int j = 0; j < 4; j++) {                                            \
        atomicAdd(&colsum[wn + j * 16 + lrow], csum[j]);                     \
        atomicAdd(&colsq[wn + j * 16 + lrow], csq[j]);                       \
    }                                                                        \
    __syncthreads();                                                         \
    if (tid < 128) {                                                         \
        float* st = stats + (blockIdx.y & 7) * 512;                          \
        atomicAdd(&st[col0 + tid], colsum[tid]);                             \
        atomicAdd(&st[DIM + col0 + tid], colsq[tid]);                        \
    }

// Stage one BK=32 K-step (16 KB: A 8K + B 8K) into buffer `buf`.
// Per wave: 2 issues x (A,B); LDS dest = wave-uniform base, lane x 16B.
#define STAGE32(buf, k)                                                      \
    _Pragma("unroll")                                                        \
    for (int j = 0; j < 2; j++) {                                            \
        int sbase = wid * 128 + j * 64;                                      \
        int s = sbase + lane;                                                \
        int m = s >> 2;                                                      \
        int c = (s & 3) ^ (m & 3);                                           \
        size_t go = (size_t)(row0 + m) * 512 + (k) * 64 + c * 16;            \
        async16(Ab + go, (char*)smem + (buf) * 16384 + sbase * 16);          \
        size_t gob = (size_t)(col0 + m) * 512 + (k) * 64 + c * 16;           \
        async16(Bb + gob, (char*)smem + (buf) * 16384 + 8192 + sbase * 16);  \
    }

__global__ __launch_bounds__(256) void gemm_f16(const _Float16* __restrict__ A,
                                                const _Float16* __restrict__ Wt,
                                                const float* __restrict__ bias,
                                                _Float16* __restrict__ C,
                                                float* __restrict__ stats,
                                                int M) {
    __shared__ uint4 smem[2240];  // 35840 B; staging dbuf uses 32768

    int tid = threadIdx.x;
    int wid = tid >> 6, lane = tid & 63;
    int quad = lane >> 4, lrow = lane & 15;
    int row0 = blockIdx.y * 128, col0 = blockIdx.x * 128;
    int wm = (wid & 1) * 64, wn = (wid >> 1) * 64;

    f32x4 acc[4][4] = {};
    const char* Ab = (const char*)A;
    const char* Bb = (const char*)Wt;

    STAGE32(0, 0);
    __syncthreads();
#pragma unroll
    for (int k = 0; k < 8; k++) {
        int buf = k & 1;
        if (k < 7) STAGE32(buf ^ 1, k + 1);
        half8 af[4], bf[4];
#pragma unroll
        for (int t = 0; t < 4; t++) {
            int ma = wm + t * 16 + lrow;
            af[t] = *(const half8*)((const char*)smem + buf * 16384 +
                                    (ma * 4 + (quad ^ (ma & 3))) * 16);
            int mb = wn + t * 16 + lrow;
            bf[t] = *(const half8*)((const char*)smem + buf * 16384 + 8192 +
                                    (mb * 4 + (quad ^ (mb & 3))) * 16);
        }
#pragma unroll
        for (int i = 0; i < 4; i++)
#pragma unroll
            for (int j2 = 0; j2 < 4; j2++)
                acc[i][j2] = __builtin_amdgcn_mfma_f32_16x16x32_f16(
                    af[i], bf[j2], acc[i][j2], 0, 0, 0);
        if (k < 7) __syncthreads();
    }

    GEMM_EPILOGUE
}

// Same pipelined GEMM; BN1 finalized IN-BLOCK from statsIn (782 blocks x
// 16KB = cheap) into LDS, applied to the A-operand as scale/shift+ReLU.
// scv/shv indexed by the fully-unrolled k -> static (rule #20).
__global__ __launch_bounds__(256) void gemm_bn(const _Float16* __restrict__ A,
                                               const _Float16* __restrict__ Wt,
                                               const float* __restrict__ bias,
                                               _Float16* __restrict__ C,
                                               float* __restrict__ stats,
                                               const float* __restrict__ statsIn,
                                               const float* __restrict__ gamma1,
                                               const float* __restrict__ beta1,
                                               int M) {
    __shared__ uint4 smem[2368];  // 35840 B staging/epi + 2048 B scshL

    int tid = threadIdx.x;
    int wid = tid >> 6, lane = tid & 63;
    int quad = lane >> 4, lrow = lane & 15;
    int row0 = blockIdx.y * 128, col0 = blockIdx.x * 128;
    int wm = (wid & 1) * 64, wn = (wid >> 1) * 64;

    // In-block BN1 finalize -> LDS (region disjoint from staging/epilogue)
    float* scshL = (float*)((char*)smem + 35840);
    bn_finalize_thread(statsIn, gamma1, beta1, scshL, tid, M);
    __syncthreads();

    // Per-lane BN1 scale/shift fragments for all 8 K=32 steps (fp16, regs)
    half8 scv[8], shv[8];
#pragma unroll
    for (int cc = 0; cc < 8; cc++) {
        int kk = cc * 32 + quad * 8;
        float4 s0 = *(const float4*)(scshL + kk);
        float4 s1 = *(const float4*)(scshL + kk + 4);
        float4 h0 = *(const float4*)(scshL + DIM + kk);
        float4 h1 = *(const float4*)(scshL + DIM + kk + 4);
        half8 sv = {(_Float16)s0.x, (_Float16)s0.y, (_Float16)s0.z, (_Float16)s0.w,
                    (_Float16)s1.x, (_Float16)s1.y, (_Float16)s1.z, (_Float16)s1.w};
        half8 hv = {(_Float16)h0.x, (_Float16)h0.y, (_Float16)h0.z, (_Float16)h0.w,
                    (_Float16)h1.x, (_Float16)h1.y, (_Float16)h1.z, (_Float16)h1.w};
        scv[cc] = sv;
        shv[cc] = hv;
    }

    f32x4 acc[4][4] = {};
    const char* Ab = (const char*)A;
    const char* Bb = (const char*)Wt;
    const half8 zerov = {0, 0, 0, 0, 0, 0, 0, 0};

    STAGE32(0, 0);
    __syncthreads();
#pragma unroll
    for (int k = 0; k < 8; k++) {
        int buf = k & 1;
        if (k < 7) STAGE32(buf ^ 1, k + 1);
        half8 af[4], bf[4];
        half8 sv = scv[k];
        half8 hv = shv[k];
#pragma unroll
        for (int t = 0; t < 4; t++) {
            int ma = wm + t * 16 + lrow;
            half8 a = *(const half8*)((const char*)smem + buf * 16384 +
                                      (ma * 4 + (quad ^ (ma & 3))) * 16);
            af[t] = __builtin_elementwise_max(a * sv + hv, zerov);
            int mb = wn + t * 16 + lrow;
            bf[t] = *(const half8*)((const char*)smem + buf * 16384 + 8192 +
                                    (mb * 4 + (quad ^ (mb & 3))) * 16);
        }
#pragma unroll
        for (int i = 0; i < 4; i++)
#pragma unroll
            for (int j2 = 0; j2 < 4; j2++)
                acc[i][j2] = __builtin_amdgcn_mfma_f32_16x16x32_f16(
                    af[i], bf[j2], acc[i][j2], 0, 0, 0);
        if (k < 7) __syncthreads();
    }

    GEMM_EPILOGUE
}

// ---------------------------------------------------------------------------
// Finalize BN2 from per-layer replicated stats (1 block; stats single-use,
// per-layer buffers zeroed by the upfront memset).
// ---------------------------------------------------------------------------
__global__ __launch_bounds__(256) void bn_finalize(const float* __restrict__ stats,
                                                   const float* __restrict__ g,
                                                   const float* __restrict__ beta,
                                                   float* __restrict__ scsh,
                                                   int n) {
    int d = threadIdx.x;
    float s = 0.0f, sq = 0.0f;
#pragma unroll
    for (int r = 0; r < 8; r++) {
        s += stats[r * 512 + d];
        sq += stats[r * 512 + 256 + d];
    }
    float invn = 1.0f / (float)n;
    float mean = s * invn;
    float var = sq * invn - mean * mean;
    float inv = rsqrtf(var + 1e-5f);
    float scale = g[d] * inv;
    scsh[d] = scale;
    scsh[DIM + d] = beta[d] - mean * scale;
}

// ---------------------------------------------------------------------------
// Final BN apply (layer 4): no relu, fp32 out.  [round-6 form]
// ---------------------------------------------------------------------------
__global__ __launch_bounds__(256) void bn_apply_f(const _Float16* __restrict__ in,
                                                  float* __restrict__ outf,
                                                  const float* __restrict__ scsh) {
    size_t i = (size_t)blockIdx.x * 256 + threadIdx.x;
    int c4 = (int)(i & 63);
    float4 sc = ((const float4*)scsh)[c4];
    float4 sh = ((const float4*)(scsh + DIM))[c4];
    half4 v = ((const half4*)in)[i];
    float4 o;
    o.x = (float)v.x * sc.x + sh.x;
    o.y = (float)v.y * sc.y + sh.y;
    o.z = (float)v.z * sc.z + sh.z;
    o.w = (float)v.w * sc.w + sh.w;
    ((float4*)outf)[i] = o;
}

// ---------------------------------------------------------------------------
extern "C" void kernel_launch(void* const* d_in, const int* in_sizes, int n_in,
                              void* d_out, int out_size, void* d_ws, size_t ws_size,
                              hipStream_t stream) {
    (void)in_sizes; (void)n_in; (void)out_size; (void)ws_size;
    const float* x   = (const float*)d_in[0];
    const int*   src = (const int*)d_in[1];
    const int*   dst = (const int*)d_in[2];
    const float* W1  = (const float*)d_in[3];
    const float* b1  = (const float*)d_in[4];
    const float* g1  = (const float*)d_in[5];
    const float* bt1 = (const float*)d_in[6];
    const float* W2  = (const float*)d_in[7];
    const float* b2  = (const float*)d_in[8];
    const float* eps = (const float*)d_in[9];
    const float* bng = (const float*)d_in[10];
    const float* bnb = (const float*)d_in[11];
    float* out = (float*)d_out;

    const int N = N_NODES, E = N_EDGES, D = DIM;
    size_t NDp = (size_t)MPAD * D;

    _Float16* gin  = (_Float16*)d_ws;              // gather output / GEMM1 in
    _Float16* C1   = gin + NDp;                    // GEMM1 raw out (also xh @ l0)
    _Float16* C2   = C1 + NDp;                     // GEMM2 raw out
    _Float16* Wt   = C2 + NDp;                     // 10 * 256*256 fp16
    // [statsA(5 layers) | statsB(5 layers) | deg] contiguous -> one memset
    float* statsA  = (float*)(Wt + 10 * 65536);    // 5 * 8 * 512 f (BN1)
    float* statsB  = statsA + 5 * 4096;            // 5 * 8 * 512 f (BN2)
    int* deg       = (int*)(statsB + 5 * 4096);    // N (cursor)
    int* ptr       = deg + N;                      // N+1
    int* bsum      = ptr + N + 1;                  // 64
    int* srcbuf    = bsum + 64;                    // E
    float* scshB   = (float*)(srcbuf + E);         // 512 f (BN2 scale/shift)

    const int ELEM4_BLOCKS = N * D / 4 / 256;      // 12500
    const int NODE_BLOCKS  = (N + 3) / 4;          // 12500
    const int E_BLOCKS     = (E + 255) / 256;      // 1172
    const int SCAN_BLOCKS  = (N + 1023) / 1024;    // 49
    const dim3 GEMM_GRID(2, MPAD / 128);           // (2, 391)

    // ---- One-time per call: zero all per-layer stats + deg, CSR, prep ----
    hipMemsetAsync(statsA, 0, (size_t)(10 * 4096 + N) * sizeof(float), stream);
    hist_dst<<<E_BLOCKS, 256, 0, stream>>>(dst, deg, E);
    scan_blk<<<SCAN_BLOCKS, 1024, 0, stream>>>(deg, ptr, bsum, N);
    scan_add<<<SCAN_BLOCKS, 1024, 0, stream>>>(ptr, bsum, deg, N, E);
    scatter_src<<<E_BLOCKS, 256, 0, stream>>>(src, dst, deg, srcbuf, E);
    prep<<<160 + ELEM4_BLOCKS, 256, 0, stream>>>(W1, W2, Wt, x, C1);  // C1 = xh

    for (int l = 0; l < 5; l++) {
        float* stA = statsA + (size_t)l * 4096;
        float* stB = statsB + (size_t)l * 4096;

        // Gather (+ fused BN2-of-previous-layer via scshB for l>=1)
        if (l == 0)
            gather_h<<<NODE_BLOCKS, 256, 0, stream>>>(C1, ptr, srcbuf, gin, eps);
        else
            gather_bn<<<NODE_BLOCKS, 256, 0, stream>>>(C2, ptr, srcbuf, gin,
                                                       scshB, eps, l);

        // C1 = gin @ W1 + b1 (raw), fused BN1 stats -> statsA[l]
        gemm_f16<<<GEMM_GRID, 256, 0, stream>>>(
            gin, Wt + (size_t)l * 65536, b1 + (size_t)l * D, C1, stA, N);

        // C2 = relu(BN1(C1)) @ W2 + b2 (raw); BN1 finalized in-block from
        // statsA[l]; fused BN2 stats -> statsB[l]
        gemm_bn<<<GEMM_GRID, 256, 0, stream>>>(
            C1, Wt + (size_t)(5 + l) * 65536, b2 + (size_t)l * D, C2,
            stB, stA, g1 + (size_t)l * D, bt1 + (size_t)l * D, N);

        // BN2 scale/shift for the next gather (or final apply)
        bn_finalize<<<1, 256, 0, stream>>>(stB, bng + (size_t)l * D,
                                           bnb + (size_t)l * D, scshB, N);

        if (l == 4)
            bn_apply_f<<<ELEM4_BLOCKS, 256, 0, stream>>>(C2, out, scshB);
    }
}